// Round 4
// baseline (207.223 us; speedup 1.0000x reference)
//
#include <hip/hip_runtime.h>
#include <stdint.h>

typedef short bf8v __attribute__((ext_vector_type(8)));
typedef float f4v  __attribute__((ext_vector_type(4)));
typedef short s8v  __attribute__((ext_vector_type(8)));
typedef short s4v  __attribute__((ext_vector_type(4)));
typedef int   i2v  __attribute__((ext_vector_type(2)));

__device__ __forceinline__ float bf2f(short b){
  unsigned u = ((unsigned)(unsigned short)b) << 16;
  union { unsigned u; float f; } c; c.u = u; return c.f;
}
__device__ __forceinline__ short f2bf(float f){
  union { float f; unsigned u; } c; c.f = f;
  unsigned r = (c.u + 0x7FFFu + ((c.u >> 16) & 1u)) >> 16;
  return (short)r;
}
__device__ __forceinline__ void gload16(const short* g, short* l){
  __builtin_amdgcn_global_load_lds(
      (const __attribute__((address_space(1))) void*)g,
      (__attribute__((address_space(3))) void*)l, 16, 0, 0);
}

// ---------------- prep: lengths -> offsets (int32/int64 autodetect) ----------
__global__ void prep_kernel(const int* lx, const int* lm, int* meta){
  if (threadIdx.x != 0) return;
  int is64 = ((lx[1] | lx[3] | lx[5] | lx[7]) == 0) ? 1 : 0;
  int ox = 0, om = 0;
  for (int b = 0; b < 8; ++b){
    int a = is64 ? lx[2*b] : lx[b];
    int c = is64 ? lm[2*b] : lm[b];
    meta[b] = a; meta[8+b] = c;
    meta[16+b] = ox; meta[25+b] = om;
    ox += a; om += c;
  }
  meta[24] = ox; meta[33] = om;
}

// ---------------- f32 -> bf16 conversion for x and mem -----------------------
__global__ __launch_bounds__(256) void cvt2bf(const float* __restrict__ x,
                                              const float* __restrict__ mem,
                                              short* __restrict__ xb,
                                              short* __restrict__ mb,
                                              long long n){
  long long t = (long long)blockIdx.x * 256 + threadIdx.x;
  long long i = t * 8;
  const float* s; short* d;
  if (i < n){ s = x + i; d = xb + i; }
  else {
    i -= n; if (i >= n) return;
    s = mem + i; d = mb + i;
  }
  float4 f0 = *(const float4*)s;
  float4 f1 = *(const float4*)(s + 4);
  s8v o;
  o[0]=f2bf(f0.x); o[1]=f2bf(f0.y); o[2]=f2bf(f0.z); o[3]=f2bf(f0.w);
  o[4]=f2bf(f1.x); o[5]=f2bf(f1.y); o[6]=f2bf(f1.z); o[7]=f2bf(f1.w);
  *(s8v*)d = o;
}

// ---------------- weight transpose + convert: W[K][N] -> WT[N][K] bf16 -------
__global__ __launch_bounds__(256) void cvt_w_t(
    const float* __restrict__ Wq, const float* __restrict__ Wk,
    const float* __restrict__ Wv, const float* __restrict__ Wo,
    const float* __restrict__ W1, const float* __restrict__ W2,
    short* __restrict__ WqT, short* __restrict__ WkT,
    short* __restrict__ WvT, short* __restrict__ WoT,
    short* __restrict__ W1T, short* __restrict__ W2T){
  __shared__ float tile[32][33];
  int bid = blockIdx.x;
  const float* W; short* WT; int K, N, t0;
  if      (bid <  256){ W=Wq; WT=WqT; K=512;  N=512;  t0=0;    }
  else if (bid <  512){ W=Wk; WT=WkT; K=512;  N=512;  t0=256;  }
  else if (bid <  768){ W=Wv; WT=WvT; K=512;  N=512;  t0=512;  }
  else if (bid < 1024){ W=Wo; WT=WoT; K=512;  N=512;  t0=768;  }
  else if (bid < 2048){ W=W1; WT=W1T; K=512;  N=2048; t0=1024; }
  else                { W=W2; WT=W2T; K=2048; N=512;  t0=2048; }
  int lt = bid - t0;
  int ntn = N / 32;
  int tk = lt / ntn, tn = lt % ntn;
  int r0 = threadIdx.x >> 5, c = threadIdx.x & 31;
  #pragma unroll
  for (int i = 0; i < 4; ++i){
    int r = r0 + i*8;
    tile[r][c] = W[(long)(tk*32 + r)*N + tn*32 + c];
  }
  __syncthreads();
  #pragma unroll
  for (int i = 0; i < 4; ++i){
    int r = r0 + i*8;
    WT[(long)(tn*32 + r)*K + tk*32 + c] = f2bf(tile[c][r]);
  }
}

// ---------------- generic bf16 MFMA GEMM core: C[M,N] = A[M,K] @ Bt[N,K]^T ---
template<int BM>
__device__ __forceinline__ void stage_gemm(const short* A, const short* Bt,
    long brow, long bcol, int M, int N, int K, int t,
    short* Als, short* Bls){
  int tid = threadIdx.x;
  #pragma unroll
  for (int i = 0; i < BM/64; ++i){
    int cc = i*256 + tid;
    int row = cc >> 2, slot = cc & 3;
    int cg = slot ^ ((row >> 1) & 3);
    long ar = brow + row; if (ar >= M) ar = M - 1;
    gload16(A + ar*(long)K + t + cg*8, &Als[cc*8]);
  }
  #pragma unroll
  for (int i = 0; i < 2; ++i){
    int cc = i*256 + tid;
    int row = cc >> 2, slot = cc & 3;
    int cg = slot ^ ((row >> 1) & 3);
    long br = bcol + row; if (br >= N) br = N - 1;
    gload16(Bt + br*(long)K + t + cg*8, &Bls[cc*8]);
  }
}

template<int BM>
__device__ __forceinline__ void gemm_core(const short* A, const short* Bt,
    short* __restrict__ C, const float* __restrict__ bias,
    int M, int N, int K, float scale, int relu, int colmajor,
    long brow, long bcol, short* Als, short* Bls){
  constexpr int NREP = (BM == 128) ? 4 : 2;
  int tid = threadIdx.x;
  int lane = tid & 63, w = tid >> 6;
  int wrow = (BM == 128) ? (w >> 1) * 64 : 0;
  int wcol = (BM == 128) ? (w & 1) * 64 : w * 32;
  int l15 = lane & 15, l4 = lane >> 4;

  f4v acc[4][NREP];
  #pragma unroll
  for (int m = 0; m < 4; ++m)
    #pragma unroll
    for (int n = 0; n < NREP; ++n) acc[m][n] = (f4v){0.f,0.f,0.f,0.f};

  int nt = K / 32;
  stage_gemm<BM>(A, Bt, brow, bcol, M, N, K, 0, Als, Bls);
  for (int t = 0; t < nt; ++t){
    __syncthreads();
    if (t + 1 < nt)
      stage_gemm<BM>(A, Bt, brow, bcol, M, N, K, (t+1)*32,
                     Als + ((t+1)&1)*(BM*32), Bls + ((t+1)&1)*4096);
    const short* Ab = Als + (t&1)*(BM*32);
    const short* Bb = Bls + (t&1)*4096;
    bf8v a[4], b[NREP];
    #pragma unroll
    for (int m = 0; m < 4; ++m){
      int row = wrow + m*16 + l15;
      int slot = l4 ^ ((row >> 1) & 3);
      a[m] = *(const bf8v*)&Ab[row*32 + slot*8];
    }
    #pragma unroll
    for (int n = 0; n < NREP; ++n){
      int row = wcol + n*16 + l15;
      int slot = l4 ^ ((row >> 1) & 3);
      b[n] = *(const bf8v*)&Bb[row*32 + slot*8];
    }
    #pragma unroll
    for (int m = 0; m < 4; ++m)
      #pragma unroll
      for (int n = 0; n < NREP; ++n)
        acc[m][n] = __builtin_amdgcn_mfma_f32_16x16x32_bf16(a[m], b[n], acc[m][n], 0, 0, 0);
  }

  #pragma unroll
  for (int m = 0; m < 4; ++m){
    #pragma unroll
    for (int n = 0; n < NREP; ++n){
      long col = bcol + wcol + n*16 + l15;
      float bi = (bias != nullptr && col < N) ? bias[col] : 0.f;
      #pragma unroll
      for (int j = 0; j < 4; ++j){
        long row = brow + wrow + m*16 + 4*l4 + j;
        if (row < M && col < N){
          float v = acc[m][n][j] * scale + bi;
          if (relu) v = fmaxf(v, 0.f);
          C[colmajor ? (col*(long)M + row) : (row*(long)N + col)] = f2bf(v);
        }
      }
    }
  }
}

__global__ __launch_bounds__(256) void gemm_bt(
    const short* __restrict__ A, const short* __restrict__ Bt,
    short* __restrict__ C, const float* __restrict__ bias,
    int M, int N, int K, float scale, int relu, int colmajor){
  __shared__ __align__(16) short Als[2*128*32];
  __shared__ __align__(16) short Bls[2*128*32];
  gemm_core<128>(A, Bt, C, bias, M, N, K, scale, relu, colmajor,
                 (long)blockIdx.y * 128, (long)blockIdx.x * 128, Als, Bls);
}

__global__ __launch_bounds__(256) void gemm_bt64(
    const short* __restrict__ A, const short* __restrict__ Bt,
    short* __restrict__ C, const float* __restrict__ bias,
    int M, int N, int K, float scale, int relu, int colmajor){
  __shared__ __align__(16) short Als[2*64*32];
  __shared__ __align__(16) short Bls[2*128*32];
  gemm_core<64>(A, Bt, C, bias, M, N, K, scale, relu, colmajor,
                (long)blockIdx.y * 64, (long)blockIdx.x * 128, Als, Bls);
}

// fused QKV (BM=64): grid.x = 12 (4 col-tiles x {Q,K,V}); Q from xb, K/V from mb.
__global__ __launch_bounds__(256) void gemm_qkv(
    const short* __restrict__ xb, const short* __restrict__ mb,
    const short* __restrict__ WqT, const short* __restrict__ WkT,
    const short* __restrict__ WvT,
    short* __restrict__ Qb, short* __restrict__ Kbf, short* __restrict__ Vtb,
    int total){
  __shared__ __align__(16) short Als[2*64*32];
  __shared__ __align__(16) short Bls[2*128*32];
  int seg = blockIdx.x >> 2;
  const short* A  = (seg == 0) ? xb : mb;
  const short* Bt = (seg == 0) ? WqT : ((seg == 1) ? WkT : WvT);
  short* C        = (seg == 0) ? Qb  : ((seg == 1) ? Kbf : Vtb);
  float scale     = (seg == 0) ? 0.125f : 1.f;
  int colmajor    = (seg == 2);
  gemm_core<64>(A, Bt, C, nullptr, total, 512, 512, scale, 0, colmajor,
                (long)blockIdx.y * 64, (long)(blockIdx.x & 3) * 128, Als, Bls);
}

// ---------------- flash attention, barrier-free ------------------------------
// grid = (h + 8*b, qtile of 128); 4 independent waves x 32 q-rows each.
// K,V fragments loaded global->VGPR directly (L1/L2-resident tiles);
// swapped QK^T: S^T = mfma(K, Q) so softmax rows are lane-local columns;
// P^T round-trips through a wave-private 4KB LDS tile. No __syncthreads.
__global__ __launch_bounds__(256, 2) void attn_kernel(
    const short* __restrict__ Q, const short* __restrict__ Kb,
    const short* __restrict__ Vt, short* __restrict__ Ob,
    const int* __restrict__ meta, int total){
  int hb = blockIdx.x;
  int h = hb & 7, b = hb >> 3;
  int qt = blockIdx.y;
  int Lx = meta[b], Lm = meta[8+b];
  int ox = meta[16+b], om = meta[25+b];
  int tid = threadIdx.x;
  int lane = tid & 63, w = tid >> 6;
  int l15 = lane & 15, l4 = lane >> 4;
  int qbase = qt*128 + w*32;
  if (qbase >= Lx) return;

  __shared__ __align__(16) short Pls[4][32*64];   // per-wave P^T [32q][64kv]
  short* pls = Pls[w];

  // Q fragments (B-operand of swapped QK^T): col=l15 -> q, k=l4*8+j -> dh
  bf8v aq[2][2];
  #pragma unroll
  for (int mi = 0; mi < 2; ++mi){
    int qr = qbase + mi*16 + l15;
    int grow = ox + (qr < Lx ? qr : Lx - 1);
    const short* qp = Q + (long)grow*512 + h*64 + l4*8;
    aq[mi][0] = *(const bf8v*)qp;
    aq[mi][1] = *(const bf8v*)(qp + 32);
  }
  float mrun[2] = {-1e30f, -1e30f};
  float lrun[2] = {0.f, 0.f};
  f4v o[2][4];
  #pragma unroll
  for (int mi = 0; mi < 2; ++mi)
    #pragma unroll
    for (int n = 0; n < 4; ++n) o[mi][n] = (f4v){0.f,0.f,0.f,0.f};

  int nt = (Lm + 63) / 64;
  for (int t = 0; t < nt; ++t){
    int kv0 = t * 64;

    // S^T[kv][q] = K @ Q^T : A-frag = K row (row=l15 -> kv), per n-block of 16
    f4v s[2][4];
    #pragma unroll
    for (int n = 0; n < 4; ++n){
      int kvr = kv0 + n*16 + l15; if (kvr >= Lm) kvr = Lm - 1;
      const short* kp = Kb + (long)(om + kvr)*512 + h*64 + l4*8;
      bf8v k0 = *(const bf8v*)kp;
      bf8v k1 = *(const bf8v*)(kp + 32);
      #pragma unroll
      for (int mi = 0; mi < 2; ++mi){
        f4v z = (f4v){0.f,0.f,0.f,0.f};
        z = __builtin_amdgcn_mfma_f32_16x16x32_bf16(k0, aq[mi][0], z, 0, 0, 0);
        z = __builtin_amdgcn_mfma_f32_16x16x32_bf16(k1, aq[mi][1], z, 0, 0, 0);
        s[mi][n] = z;
      }
    }

    // mask invalid kv rows (only possible on the last tile); kv = n*16+4*l4+j
    if (kv0 + 64 > Lm){
      #pragma unroll
      for (int n = 0; n < 4; ++n){
        int kvb = kv0 + n*16 + 4*l4;
        #pragma unroll
        for (int j = 0; j < 4; ++j)
          if (kvb + j >= Lm){ s[0][n][j] = -1e30f; s[1][n][j] = -1e30f; }
      }
    }

    // online softmax per q (= lane's l15 within mi-block); reduce over 16
    // in-register kv values then across the 4 l4-groups (xor 16, 32).
    #pragma unroll
    for (int mi = 0; mi < 2; ++mi){
      float m1 = s[mi][0][0];
      #pragma unroll
      for (int n = 0; n < 4; ++n)
        #pragma unroll
        for (int j = 0; j < 4; ++j) m1 = fmaxf(m1, s[mi][n][j]);
      m1 = fmaxf(m1, __shfl_xor(m1, 16, 64));
      m1 = fmaxf(m1, __shfl_xor(m1, 32, 64));
      float mnew = fmaxf(mrun[mi], m1);
      float sc = __expf(mrun[mi] - mnew);
      mrun[mi] = mnew;
      float rs = 0.f;
      #pragma unroll
      for (int n = 0; n < 4; ++n)
        #pragma unroll
        for (int j = 0; j < 4; ++j){
          float p = __expf(s[mi][n][j] - mnew);
          s[mi][n][j] = p; rs += p;
        }
      rs += __shfl_xor(rs, 16, 64);
      rs += __shfl_xor(rs, 32, 64);
      lrun[mi] = lrun[mi] * sc + rs;
      #pragma unroll
      for (int n = 0; n < 4; ++n) o[mi][n] *= sc;

      // write P^T row q: 4 consecutive kv per (n) -> one b64, chunk-swizzled
      int q = mi*16 + l15;
      #pragma unroll
      for (int n = 0; n < 4; ++n){
        unsigned r0, r1;
        asm("v_cvt_pk_bf16_f32 %0, %1, %2" : "=v"(r0) : "v"(s[mi][n][0]), "v"(s[mi][n][1]));
        asm("v_cvt_pk_bf16_f32 %0, %1, %2" : "=v"(r1) : "v"(s[mi][n][2]), "v"(s[mi][n][3]));
        i2v pr; pr[0] = (int)r0; pr[1] = (int)r1;
        *(i2v*)&pls[q*64 + ((n ^ (l15 & 3)) << 4) + (l4 << 2)] = pr;
      }
    }

    // P^T B-frags: col=l15 -> q, k = ks*32 + l4*8 + j -> kv
    bf8v pb[2][2];
    #pragma unroll
    for (int mi = 0; mi < 2; ++mi)
      #pragma unroll
      for (int ks = 0; ks < 2; ++ks){
        int q = mi*16 + l15;
        int ch = (ks*2 + (l4 >> 1)) ^ (q & 3);
        pb[mi][ks] = *(const bf8v*)&pls[q*64 + (ch << 4) + ((l4 & 1) << 3)];
      }

    // O^T += V^T @ P^T : A-frag = Vt row (row=l15 -> d), k -> kv
    #pragma unroll
    for (int n2 = 0; n2 < 4; ++n2){
      const short* vp = Vt + (long)(h*64 + n2*16 + l15)*total + om;
      #pragma unroll
      for (int ks = 0; ks < 2; ++ks){
        int vk = kv0 + ks*32 + l4*8;
        if (vk + 8 > Lm) vk = (Lm - 8) & ~0; // stay in-batch; P zeros kill it
        bf8v vv = *(const bf8v*)(vp + vk);
        o[0][n2] = __builtin_amdgcn_mfma_f32_16x16x32_bf16(vv, pb[0][ks], o[0][n2], 0, 0, 0);
        o[1][n2] = __builtin_amdgcn_mfma_f32_16x16x32_bf16(vv, pb[1][ks], o[1][n2], 0, 0, 0);
      }
    }
  }

  // epilogue: O^T frag (col=l15 -> q, row=4*l4+j -> d), j-contiguous stores
  #pragma unroll
  for (int mi = 0; mi < 2; ++mi){
    int qr = qbase + mi*16 + l15;
    if (qr < Lx){
      float inv = 1.f / lrun[mi];
      long obase = (long)(ox + qr)*512 + h*64;
      #pragma unroll
      for (int n2 = 0; n2 < 4; ++n2){
        s4v ov;
        #pragma unroll
        for (int j = 0; j < 4; ++j) ov[j] = f2bf(o[mi][n2][j] * inv);
        *(s4v*)&Ob[obase + n2*16 + (l4 << 2)] = ov;
      }
    }
  }
}

// ---------------- fused residual + LayerNorm (wave per 512-col row) ----------
__global__ __launch_bounds__(256) void ln_fuse(
    const float* __restrict__ Af, const short* __restrict__ Ab,
    const short* __restrict__ Bb,
    const float* __restrict__ gamma, const float* __restrict__ beta,
    short* __restrict__ outb, float* __restrict__ outf, int rows){
  int w = threadIdx.x >> 6, lane = threadIdx.x & 63;
  long row = (long)blockIdx.x * 4 + w;
  if (row >= rows) return;
  int c0 = lane * 8;
  long base = row * 512 + c0;
  float v[8];
  if (Af){
    float4 f0 = *(const float4*)(Af + base);
    float4 f1 = *(const float4*)(Af + base + 4);
    v[0]=f0.x; v[1]=f0.y; v[2]=f0.z; v[3]=f0.w;
    v[4]=f1.x; v[5]=f1.y; v[6]=f1.z; v[7]=f1.w;
  } else {
    s8v a = *(const s8v*)(Ab + base);
    #pragma unroll
    for (int j = 0; j < 8; ++j) v[j] = bf2f(a[j]);
  }
  s8v bb = *(const s8v*)(Bb + base);
  #pragma unroll
  for (int j = 0; j < 8; ++j) v[j] += bf2f(bb[j]);
  float sum = 0.f;
  #pragma unroll
  for (int j = 0; j < 8; ++j) sum += v[j];
  #pragma unroll
  for (int m = 1; m < 64; m <<= 1) sum += __shfl_xor(sum, m, 64);
  float mu = sum * (1.f/512.f);
  float q = 0.f;
  #pragma unroll
  for (int j = 0; j < 8; ++j){ float d = v[j] - mu; q += d*d; }
  #pragma unroll
  for (int m = 1; m < 64; m <<= 1) q += __shfl_xor(q, m, 64);
  float rs = rsqrtf(q * (1.f/512.f) + 1e-6f);
  float ov[8];
  #pragma unroll
  for (int j = 0; j < 8; ++j)
    ov[j] = (v[j] - mu) * rs * gamma[c0 + j] + beta[c0 + j];
  if (outb){
    s8v os;
    #pragma unroll
    for (int j = 0; j < 8; ++j) os[j] = f2bf(ov[j]);
    *(s8v*)(outb + base) = os;
  } else {
    float4 f0 = {ov[0], ov[1], ov[2], ov[3]};
    float4 f1 = {ov[4], ov[5], ov[6], ov[7]};
    *(float4*)(outf + base) = f0;
    *(float4*)(outf + base + 4) = f1;
  }
}

// ---------------- host ------------------------------------------------------
extern "C" void kernel_launch(void* const* d_in, const int* in_sizes, int n_in,
                              void* d_out, int out_size, void* d_ws, size_t ws_size,
                              hipStream_t stream){
  (void)n_in; (void)out_size; (void)ws_size;
  const float* x   = (const float*)d_in[0];
  const float* mem = (const float*)d_in[1];
  const int*   lxr = (const int*)d_in[2];
  const int*   lmr = (const int*)d_in[3];
  const float* Wq  = (const float*)d_in[4];
  const float* Wk  = (const float*)d_in[5];
  const float* Wv  = (const float*)d_in[6];
  const float* Wo  = (const float*)d_in[7];
  const float* g1  = (const float*)d_in[8];
  const float* be1 = (const float*)d_in[9];
  const float* W1  = (const float*)d_in[10];
  const float* b1  = (const float*)d_in[11];
  const float* W2  = (const float*)d_in[12];
  const float* b2  = (const float*)d_in[13];
  const float* g2  = (const float*)d_in[14];
  const float* be2 = (const float*)d_in[15];
  float* out = (float*)d_out;

  int total = in_sizes[0] / 512;
  if (total <= 0) return;
  long long n = (long long)total * 512;

  char* p = (char*)d_ws;
  int*   meta = (int*)p;    p += 256;
  short* xb   = (short*)p;  p += n*2;
  short* mb   = (short*)p;  p += n*2;
  short* Qb   = (short*)p;  p += n*2;
  short* Kbf  = (short*)p;  p += n*2;
  short* Vtb  = (short*)p;  p += n*2;
  short* attnb= (short*)p;  p += n*2;
  short* woout= (short*)p;  p += n*2;
  short* hb   = (short*)p;  p += n*2;
  short* ffn1 = (short*)p;  p += (long long)total*2048*2;
  short* ffn2 = (short*)p;  p += n*2;
  short* WqT  = (short*)p;  p += 512*512*2;
  short* WkT  = (short*)p;  p += 512*512*2;
  short* WvT  = (short*)p;  p += 512*512*2;
  short* WoT  = (short*)p;  p += 512*512*2;
  short* W1T  = (short*)p;  p += 2048*512*2;
  short* W2T  = (short*)p;  p += 512*2048*2;

  prep_kernel<<<1, 64, 0, stream>>>(lxr, lmr, meta);

  long long th = (2*n)/8;
  cvt2bf<<<dim3((unsigned)((th + 255)/256)), dim3(256), 0, stream>>>(x, mem, xb, mb, n);
  cvt_w_t<<<dim3(3072), dim3(256), 0, stream>>>(Wq,Wk,Wv,Wo,W1,W2, WqT,WkT,WvT,WoT,W1T,W2T);

  int mt128 = (total + 127)/128;
  int mt64  = (total + 63)/64;
  gemm_qkv<<<dim3(12, mt64), 256, 0, stream>>>(xb, mb, WqT, WkT, WvT, Qb, Kbf, Vtb, total);

  attn_kernel<<<dim3(64, (unsigned)((total + 127)/128)), 256, 0, stream>>>(Qb, Kbf, Vtb, attnb, meta, total);

  gemm_bt64<<<dim3(4, mt64), 256, 0, stream>>>(attnb, WoT, woout, nullptr, total, 512, 512, 1.f, 0, 0);
  ln_fuse<<<dim3((unsigned)((total + 3)/4)), 256, 0, stream>>>(x, nullptr, woout, g1, be1, hb, nullptr, total);

  gemm_bt<<<dim3(16, mt128), 256, 0, stream>>>(hb,   W1T, ffn1, b1, total, 2048, 512,  1.f, 1, 0);
  gemm_bt64<<<dim3(4, mt64), 256, 0, stream>>>(ffn1, W2T, ffn2, b2, total, 512,  2048, 1.f, 0, 0);
  ln_fuse<<<dim3((unsigned)((total + 3)/4)), 256, 0, stream>>>(nullptr, hb, ffn2, g2, be2, nullptr, out, total);
}

// Round 5
// 179.413 us; speedup vs baseline: 1.1550x; 1.1550x over previous
//
#include <hip/hip_runtime.h>
#include <stdint.h>

typedef short bf8v __attribute__((ext_vector_type(8)));
typedef float f4v  __attribute__((ext_vector_type(4)));
typedef short s8v  __attribute__((ext_vector_type(8)));
typedef short s4v  __attribute__((ext_vector_type(4)));
typedef int   i2v  __attribute__((ext_vector_type(2)));

__device__ __forceinline__ float bf2f(short b){
  unsigned u = ((unsigned)(unsigned short)b) << 16;
  union { unsigned u; float f; } c; c.u = u; return c.f;
}
__device__ __forceinline__ short f2bf(float f){
  union { float f; unsigned u; } c; c.f = f;
  unsigned r = (c.u + 0x7FFFu + ((c.u >> 16) & 1u)) >> 16;
  return (short)r;
}
__device__ __forceinline__ void gload16(const short* g, short* l){
  __builtin_amdgcn_global_load_lds(
      (const __attribute__((address_space(1))) void*)g,
      (__attribute__((address_space(3))) void*)l, 16, 0, 0);
}

// ---------------- prep: lengths/offsets + kv-split job list -----------------
__global__ void prep_kernel(const int* lx, const int* lm, int* meta){
  __shared__ int sjp[9], skvc[8];
  int tid = threadIdx.x;
  if (tid == 0){
    int is64 = ((lx[1] | lx[3] | lx[5] | lx[7]) == 0) ? 1 : 0;
    int ox = 0, om = 0;
    for (int b = 0; b < 8; ++b){
      int a = is64 ? lx[2*b] : lx[b];
      int c = is64 ? lm[2*b] : lm[b];
      meta[b] = a; meta[8+b] = c;
      meta[16+b] = ox; meta[25+b] = om;
      ox += a; om += c;
    }
    meta[24] = ox; meta[33] = om;
    int jp = 0;
    for (int b = 0; b < 8; ++b){
      int Lm_ = meta[8+b];
      int kvc = (Lm_ + 255) / 256; if (kvc > 4) kvc = 4; if (kvc < 1) kvc = 1;
      int clen = (((Lm_ + kvc - 1) / kvc) + 31) & ~31;
      meta[34+b] = kvc; meta[42+b] = clen;
      meta[50+b] = jp;
      sjp[b] = jp; skvc[b] = kvc;
      int qt = (meta[b] + 63) / 64;
      jp += qt * kvc * 8;
    }
    meta[58] = jp;
    sjp[8] = jp;
  }
  __syncthreads();
  int njobs = sjp[8];
  for (int j = tid; j < njobs; j += blockDim.x){
    int b = 0;
    #pragma unroll
    for (int i = 1; i < 8; ++i) if (j >= sjp[i]) b = i;
    int local = j - sjp[b];
    int kvc = skvc[b];
    int h = local & 7;
    int r = local >> 3;
    int c = r % kvc;
    int qt = r / kvc;
    meta[64+j] = b | (h << 4) | (c << 7) | (qt << 11);
  }
}

// ---------------- f32 -> bf16 conversion for x and mem -----------------------
__global__ __launch_bounds__(256) void cvt2bf(const float* __restrict__ x,
                                              const float* __restrict__ mem,
                                              short* __restrict__ xb,
                                              short* __restrict__ mb,
                                              long long n){
  long long t = (long long)blockIdx.x * 256 + threadIdx.x;
  long long i = t * 8;
  const float* s; short* d;
  if (i < n){ s = x + i; d = xb + i; }
  else {
    i -= n; if (i >= n) return;
    s = mem + i; d = mb + i;
  }
  float4 f0 = *(const float4*)s;
  float4 f1 = *(const float4*)(s + 4);
  s8v o;
  o[0]=f2bf(f0.x); o[1]=f2bf(f0.y); o[2]=f2bf(f0.z); o[3]=f2bf(f0.w);
  o[4]=f2bf(f1.x); o[5]=f2bf(f1.y); o[6]=f2bf(f1.z); o[7]=f2bf(f1.w);
  *(s8v*)d = o;
}

// ---------------- weight transpose + convert: W[K][N] -> WT[N][K] bf16 -------
__global__ __launch_bounds__(256) void cvt_w_t(
    const float* __restrict__ Wq, const float* __restrict__ Wk,
    const float* __restrict__ Wv, const float* __restrict__ Wo,
    const float* __restrict__ W1, const float* __restrict__ W2,
    short* __restrict__ WqT, short* __restrict__ WkT,
    short* __restrict__ WvT, short* __restrict__ WoT,
    short* __restrict__ W1T, short* __restrict__ W2T){
  __shared__ float tile[32][33];
  int bid = blockIdx.x;
  const float* W; short* WT; int K, N, t0;
  if      (bid <  256){ W=Wq; WT=WqT; K=512;  N=512;  t0=0;    }
  else if (bid <  512){ W=Wk; WT=WkT; K=512;  N=512;  t0=256;  }
  else if (bid <  768){ W=Wv; WT=WvT; K=512;  N=512;  t0=512;  }
  else if (bid < 1024){ W=Wo; WT=WoT; K=512;  N=512;  t0=768;  }
  else if (bid < 2048){ W=W1; WT=W1T; K=512;  N=2048; t0=1024; }
  else                { W=W2; WT=W2T; K=2048; N=512;  t0=2048; }
  int lt = bid - t0;
  int ntn = N / 32;
  int tk = lt / ntn, tn = lt % ntn;
  int r0 = threadIdx.x >> 5, c = threadIdx.x & 31;
  #pragma unroll
  for (int i = 0; i < 4; ++i){
    int r = r0 + i*8;
    tile[r][c] = W[(long)(tk*32 + r)*N + tn*32 + c];
  }
  __syncthreads();
  #pragma unroll
  for (int i = 0; i < 4; ++i){
    int r = r0 + i*8;
    WT[(long)(tn*32 + r)*K + tk*32 + c] = f2bf(tile[c][r]);
  }
}

// ---------------- generic bf16 MFMA GEMM core: C[M,N] = A[M,K] @ Bt[N,K]^T ---
template<int BM>
__device__ __forceinline__ void stage_gemm(const short* A, const short* Bt,
    long brow, long bcol, int M, int N, int K, int t,
    short* Als, short* Bls){
  int tid = threadIdx.x;
  #pragma unroll
  for (int i = 0; i < BM/64; ++i){
    int cc = i*256 + tid;
    int row = cc >> 2, slot = cc & 3;
    int cg = slot ^ ((row >> 1) & 3);
    long ar = brow + row; if (ar >= M) ar = M - 1;
    gload16(A + ar*(long)K + t + cg*8, &Als[cc*8]);
  }
  #pragma unroll
  for (int i = 0; i < 2; ++i){
    int cc = i*256 + tid;
    int row = cc >> 2, slot = cc & 3;
    int cg = slot ^ ((row >> 1) & 3);
    long br = bcol + row; if (br >= N) br = N - 1;
    gload16(Bt + br*(long)K + t + cg*8, &Bls[cc*8]);
  }
}

template<int BM>
__device__ __forceinline__ void gemm_core(const short* A, const short* Bt,
    short* __restrict__ C, const float* __restrict__ bias,
    int M, int N, int K, float scale, int relu, int colmajor,
    long brow, long bcol, short* Als, short* Bls){
  constexpr int NREP = (BM == 128) ? 4 : 2;
  int tid = threadIdx.x;
  int lane = tid & 63, w = tid >> 6;
  int wrow = (BM == 128) ? (w >> 1) * 64 : 0;
  int wcol = (BM == 128) ? (w & 1) * 64 : w * 32;
  int l15 = lane & 15, l4 = lane >> 4;

  f4v acc[4][NREP];
  #pragma unroll
  for (int m = 0; m < 4; ++m)
    #pragma unroll
    for (int n = 0; n < NREP; ++n) acc[m][n] = (f4v){0.f,0.f,0.f,0.f};

  int nt = K / 32;
  stage_gemm<BM>(A, Bt, brow, bcol, M, N, K, 0, Als, Bls);
  for (int t = 0; t < nt; ++t){
    __syncthreads();
    if (t + 1 < nt)
      stage_gemm<BM>(A, Bt, brow, bcol, M, N, K, (t+1)*32,
                     Als + ((t+1)&1)*(BM*32), Bls + ((t+1)&1)*4096);
    const short* Ab = Als + (t&1)*(BM*32);
    const short* Bb = Bls + (t&1)*4096;
    bf8v a[4], b[NREP];
    #pragma unroll
    for (int m = 0; m < 4; ++m){
      int row = wrow + m*16 + l15;
      int slot = l4 ^ ((row >> 1) & 3);
      a[m] = *(const bf8v*)&Ab[row*32 + slot*8];
    }
    #pragma unroll
    for (int n = 0; n < NREP; ++n){
      int row = wcol + n*16 + l15;
      int slot = l4 ^ ((row >> 1) & 3);
      b[n] = *(const bf8v*)&Bb[row*32 + slot*8];
    }
    #pragma unroll
    for (int m = 0; m < 4; ++m)
      #pragma unroll
      for (int n = 0; n < NREP; ++n)
        acc[m][n] = __builtin_amdgcn_mfma_f32_16x16x32_bf16(a[m], b[n], acc[m][n], 0, 0, 0);
  }

  #pragma unroll
  for (int m = 0; m < 4; ++m){
    #pragma unroll
    for (int n = 0; n < NREP; ++n){
      long col = bcol + wcol + n*16 + l15;
      float bi = (bias != nullptr && col < N) ? bias[col] : 0.f;
      #pragma unroll
      for (int j = 0; j < 4; ++j){
        long row = brow + wrow + m*16 + 4*l4 + j;
        if (row < M && col < N){
          float v = acc[m][n][j] * scale + bi;
          if (relu) v = fmaxf(v, 0.f);
          C[colmajor ? (col*(long)M + row) : (row*(long)N + col)] = f2bf(v);
        }
      }
    }
  }
}

__global__ __launch_bounds__(256) void gemm_bt(
    const short* __restrict__ A, const short* __restrict__ Bt,
    short* __restrict__ C, const float* __restrict__ bias,
    int M, int N, int K, float scale, int relu, int colmajor){
  __shared__ __align__(16) short Als[2*128*32];
  __shared__ __align__(16) short Bls[2*128*32];
  gemm_core<128>(A, Bt, C, bias, M, N, K, scale, relu, colmajor,
                 (long)blockIdx.y * 128, (long)blockIdx.x * 128, Als, Bls);
}

__global__ __launch_bounds__(256) void gemm_bt64(
    const short* __restrict__ A, const short* __restrict__ Bt,
    short* __restrict__ C, const float* __restrict__ bias,
    int M, int N, int K, float scale, int relu, int colmajor){
  __shared__ __align__(16) short Als[2*64*32];
  __shared__ __align__(16) short Bls[2*128*32];
  gemm_core<64>(A, Bt, C, bias, M, N, K, scale, relu, colmajor,
                (long)blockIdx.y * 64, (long)blockIdx.x * 128, Als, Bls);
}

// fused QKV (BM=64): grid.x = 12 (4 col-tiles x {Q,K,V}); Q from xb, K/V from mb.
__global__ __launch_bounds__(256) void gemm_qkv(
    const short* __restrict__ xb, const short* __restrict__ mb,
    const short* __restrict__ WqT, const short* __restrict__ WkT,
    const short* __restrict__ WvT,
    short* __restrict__ Qb, short* __restrict__ Kbf, short* __restrict__ Vtb,
    int total){
  __shared__ __align__(16) short Als[2*64*32];
  __shared__ __align__(16) short Bls[2*128*32];
  int seg = blockIdx.x >> 2;
  const short* A  = (seg == 0) ? xb : mb;
  const short* Bt = (seg == 0) ? WqT : ((seg == 1) ? WkT : WvT);
  short* C        = (seg == 0) ? Qb  : ((seg == 1) ? Kbf : Vtb);
  float scale     = (seg == 0) ? 0.125f : 1.f;
  int colmajor    = (seg == 2);
  gemm_core<64>(A, Bt, C, nullptr, total, 512, 512, scale, 0, colmajor,
                (long)blockIdx.y * 64, (long)(blockIdx.x & 3) * 128, Als, Bls);
}

// ---------------- flash attention: split-kv jobs, swapped QK^T ---------------
// job = (b, h, qtile64, kvchunk); 4 waves x 16q; kv tile 32, double-buffered
// LDS staging. Softmax is lane-local (2 shfl). kvc==1 jobs write Ob directly;
// split jobs write bf16 partials (Opart) + (m,l) for a combine pass.
__global__ __launch_bounds__(256) void attn_kernel(
    const short* __restrict__ Q, const short* __restrict__ Kb,
    const short* __restrict__ Vt, short* __restrict__ Ob,
    short* __restrict__ Opart, float* __restrict__ mlpart,
    const int* __restrict__ meta, int total){
  __shared__ __align__(16) short Kls[2][32*64];   // [kv][dh]  rows 128B
  __shared__ __align__(16) short Vls[2][64*32];   // [dh][kv]  rows 64B
  __shared__ __align__(16) short Pls[4][16*32];   // per-wave P^T [q][kv]
  int tid = threadIdx.x;
  int lane = tid & 63, w = tid >> 6;
  int l15 = lane & 15, l4 = lane >> 4;
  int njobs = meta[58];

  for (int j = blockIdx.x; j < njobs; j += gridDim.x){
    int word = meta[64+j];
    int b = word & 15, h = (word >> 4) & 7, c = (word >> 7) & 15, qt = word >> 11;
    int Lx = meta[b], Lm = meta[8+b];
    int ox = meta[16+b], om = meta[25+b];
    int kvc = meta[34+b], clen = meta[42+b];
    int c0 = c * clen;
    int cend = c0 + clen; if (cend > Lm) cend = Lm;
    int nt = (cend - c0 + 31) / 32;
    int qbase = qt*64 + w*16;

    __syncthreads();   // previous job's LDS reads complete

    // staging: K tile (thread: row=tid>>3, slot=tid&7), V tile (row=tid>>2, slot=tid&3)
    #define ATTN_STAGE(T, BUF)                                                  \
      {                                                                         \
        int kv0_ = c0 + (T)*32;                                                 \
        int kr = tid >> 3, ks_ = tid & 7;                                       \
        int cgk = ks_ ^ (kr & 7);                                               \
        int ktok = kv0_ + kr; if (ktok >= Lm) ktok = Lm - 1;                    \
        gload16(Kb + (long)(om + ktok)*512 + h*64 + cgk*8, &Kls[BUF][tid*8]);   \
        int vr = tid >> 2, vs = tid & 3;                                        \
        int cgv = vs ^ (vr & 3);                                                \
        int vkv = kv0_ + cgv*8; if (vkv + 8 > Lm) vkv = Lm - 8;                 \
        gload16(Vt + (long)(h*64 + vr)*total + om + vkv, &Vls[BUF][tid*8]);     \
      }

    ATTN_STAGE(0, 0)

    // Q fragments (1/sqrt(dh) folded in by QKV GEMM): col=l15->q, k=l4*8+j->dh
    int qr = qbase + l15;
    const short* qp = Q + (long)(ox + (qr < Lx ? qr : Lx - 1))*512 + h*64 + l4*8;
    bf8v aq0 = *(const bf8v*)qp;
    bf8v aq1 = *(const bf8v*)(qp + 32);

    float mrun = -1e30f, lrun = 0.f;
    f4v o[4];
    #pragma unroll
    for (int n = 0; n < 4; ++n) o[n] = (f4v){0.f,0.f,0.f,0.f};

    for (int t = 0; t < nt; ++t){
      __syncthreads();                 // drains vmcnt: stage(t) ready
      if (t + 1 < nt) ATTN_STAGE(t+1, (t+1)&1)
      int buf = t & 1;
      int kv0 = c0 + t*32;

      // S^T = K @ Q^T : lane (l4,l15) gets kv = n*16+4*l4+j for q=l15
      f4v s[2];
      #pragma unroll
      for (int n = 0; n < 2; ++n){
        int krow = n*16 + l15;
        bf8v k0 = *(const bf8v*)&Kls[buf][krow*64 + ((l4    ) ^ (krow & 7))*8];
        bf8v k1 = *(const bf8v*)&Kls[buf][krow*64 + ((4 + l4) ^ (krow & 7))*8];
        f4v z = (f4v){0.f,0.f,0.f,0.f};
        z = __builtin_amdgcn_mfma_f32_16x16x32_bf16(k0, aq0, z, 0, 0, 0);
        z = __builtin_amdgcn_mfma_f32_16x16x32_bf16(k1, aq1, z, 0, 0, 0);
        s[n] = z;
      }
      // mask invalid kv (last tile only)
      if (kv0 + 32 > cend){
        #pragma unroll
        for (int n = 0; n < 2; ++n){
          int kvb = kv0 + n*16 + 4*l4;
          #pragma unroll
          for (int jj = 0; jj < 4; ++jj)
            if (kvb + jj >= cend) s[n][jj] = -1e30f;
        }
      }
      // lane-local softmax (row q = l15; combine l4 groups via xor 16,32)
      float m1 = fmaxf(fmaxf(fmaxf(s[0][0], s[0][1]), fmaxf(s[0][2], s[0][3])),
                       fmaxf(fmaxf(s[1][0], s[1][1]), fmaxf(s[1][2], s[1][3])));
      m1 = fmaxf(m1, __shfl_xor(m1, 16, 64));
      m1 = fmaxf(m1, __shfl_xor(m1, 32, 64));
      float mnew = fmaxf(mrun, m1);
      float sc = __expf(mrun - mnew);
      mrun = mnew;
      float rs = 0.f;
      #pragma unroll
      for (int n = 0; n < 2; ++n)
        #pragma unroll
        for (int jj = 0; jj < 4; ++jj){
          float p = __expf(s[n][jj] - mnew);
          s[n][jj] = p; rs += p;
        }
      rs += __shfl_xor(rs, 16, 64);
      rs += __shfl_xor(rs, 32, 64);
      lrun = lrun * sc + rs;
      #pragma unroll
      for (int n = 0; n < 4; ++n) o[n] *= sc;

      // P^T -> wave LDS: row q=l15 (64B), 8B chunk c=n*4+l4, swz c^=(q&3)<<1
      #pragma unroll
      for (int n = 0; n < 2; ++n){
        unsigned r0, r1;
        asm("v_cvt_pk_bf16_f32 %0, %1, %2" : "=v"(r0) : "v"(s[n][0]), "v"(s[n][1]));
        asm("v_cvt_pk_bf16_f32 %0, %1, %2" : "=v"(r1) : "v"(s[n][2]), "v"(s[n][3]));
        i2v pr; pr[0] = (int)r0; pr[1] = (int)r1;
        int cs = (n*4 + l4) ^ ((l15 & 3) << 1);
        *(i2v*)&Pls[w][l15*32 + cs*4] = pr;
      }
      // P^T B-frag: 16B at kv chunk-pair base 2*l4 (swizzle preserves pairs)
      bf8v pb = *(const bf8v*)&Pls[w][l15*32 + (((2*l4) ^ ((l15 & 3) << 1))*4)];

      // O^T += V^T @ P^T
      #pragma unroll
      for (int n2 = 0; n2 < 4; ++n2){
        int vrow = n2*16 + l15;
        bf8v vv = *(const bf8v*)&Vls[buf][vrow*32 + ((l4 ^ (vrow & 3))*8)];
        o[n2] = __builtin_amdgcn_mfma_f32_16x16x32_bf16(vv, pb, o[n2], 0, 0, 0);
      }
    }
    #undef ATTN_STAGE

    // epilogue: O^T frag col=l15->q, row=4*l4+jj -> d = n2*16+4*l4+jj
    if (qr < Lx){
      if (kvc == 1){
        float inv = 1.f / lrun;
        long obase = (long)(ox + qr)*512 + h*64;
        #pragma unroll
        for (int n2 = 0; n2 < 4; ++n2){
          s4v ov;
          #pragma unroll
          for (int jj = 0; jj < 4; ++jj) ov[jj] = f2bf(o[n2][jj] * inv);
          *(s4v*)&Ob[obase + n2*16 + l4*4] = ov;
        }
      } else {
        long slot = ((long)(ox + qr)*8 + h)*4 + c;
        #pragma unroll
        for (int n2 = 0; n2 < 4; ++n2){
          s4v ov;
          #pragma unroll
          for (int jj = 0; jj < 4; ++jj) ov[jj] = f2bf(o[n2][jj]);
          *(s4v*)&Opart[slot*64 + n2*16 + l4*4] = ov;
        }
        if (l4 == 0){
          float2 ml; ml.x = mrun; ml.y = lrun;
          *(float2*)&mlpart[slot*2] = ml;
        }
      }
    }
  }
}

// ---------------- combine partials for split batches -------------------------
__global__ __launch_bounds__(256) void attn_combine(
    const short* __restrict__ Opart, const float* __restrict__ mlpart,
    short* __restrict__ Ob, const int* __restrict__ meta, int total){
  int w = threadIdx.x >> 6, lane = threadIdx.x & 63;
  int row = blockIdx.x*4 + w;
  if (row >= total) return;
  int b = 0;
  #pragma unroll
  for (int i = 1; i < 8; ++i) if (row >= meta[16+i]) b = i;
  int kvc = meta[34+b];
  if (kvc <= 1) return;
  for (int h = 0; h < 8; ++h){
    long sbase = ((long)row*8 + h)*4;
    float m_ = -1e30f;
    for (int c = 0; c < kvc; ++c) m_ = fmaxf(m_, mlpart[(sbase+c)*2]);
    float num = 0.f, den = 0.f;
    for (int c = 0; c < kvc; ++c){
      float mc = mlpart[(sbase+c)*2];
      float lc = mlpart[(sbase+c)*2 + 1];
      float wgt = __expf(mc - m_);
      num += wgt * bf2f(Opart[(sbase+c)*64 + lane]);
      den += wgt * lc;
    }
    Ob[(long)row*512 + h*64 + lane] = f2bf(num / den);
  }
}

// ---------------- fused residual + LayerNorm (wave per 512-col row) ----------
__global__ __launch_bounds__(256) void ln_fuse(
    const float* __restrict__ Af, const short* __restrict__ Ab,
    const short* __restrict__ Bb,
    const float* __restrict__ gamma, const float* __restrict__ beta,
    short* __restrict__ outb, float* __restrict__ outf, int rows){
  int w = threadIdx.x >> 6, lane = threadIdx.x & 63;
  long row = (long)blockIdx.x * 4 + w;
  if (row >= rows) return;
  int c0 = lane * 8;
  long base = row * 512 + c0;
  float v[8];
  if (Af){
    float4 f0 = *(const float4*)(Af + base);
    float4 f1 = *(const float4*)(Af + base + 4);
    v[0]=f0.x; v[1]=f0.y; v[2]=f0.z; v[3]=f0.w;
    v[4]=f1.x; v[5]=f1.y; v[6]=f1.z; v[7]=f1.w;
  } else {
    s8v a = *(const s8v*)(Ab + base);
    #pragma unroll
    for (int j = 0; j < 8; ++j) v[j] = bf2f(a[j]);
  }
  s8v bb = *(const s8v*)(Bb + base);
  #pragma unroll
  for (int j = 0; j < 8; ++j) v[j] += bf2f(bb[j]);
  float sum = 0.f;
  #pragma unroll
  for (int j = 0; j < 8; ++j) sum += v[j];
  #pragma unroll
  for (int m = 1; m < 64; m <<= 1) sum += __shfl_xor(sum, m, 64);
  float mu = sum * (1.f/512.f);
  float q = 0.f;
  #pragma unroll
  for (int j = 0; j < 8; ++j){ float d = v[j] - mu; q += d*d; }
  #pragma unroll
  for (int m = 1; m < 64; m <<= 1) q += __shfl_xor(q, m, 64);
  float rs = rsqrtf(q * (1.f/512.f) + 1e-6f);
  float ov[8];
  #pragma unroll
  for (int j = 0; j < 8; ++j)
    ov[j] = (v[j] - mu) * rs * gamma[c0 + j] + beta[c0 + j];
  if (outb){
    s8v os;
    #pragma unroll
    for (int j = 0; j < 8; ++j) os[j] = f2bf(ov[j]);
    *(s8v*)(outb + base) = os;
  } else {
    float4 f0 = {ov[0], ov[1], ov[2], ov[3]};
    float4 f1 = {ov[4], ov[5], ov[6], ov[7]};
    *(float4*)(outf + base) = f0;
    *(float4*)(outf + base + 4) = f1;
  }
}

// ---------------- host ------------------------------------------------------
extern "C" void kernel_launch(void* const* d_in, const int* in_sizes, int n_in,
                              void* d_out, int out_size, void* d_ws, size_t ws_size,
                              hipStream_t stream){
  (void)n_in; (void)out_size; (void)ws_size;
  const float* x   = (const float*)d_in[0];
  const float* mem = (const float*)d_in[1];
  const int*   lxr = (const int*)d_in[2];
  const int*   lmr = (const int*)d_in[3];
  const float* Wq  = (const float*)d_in[4];
  const float* Wk  = (const float*)d_in[5];
  const float* Wv  = (const float*)d_in[6];
  const float* Wo  = (const float*)d_in[7];
  const float* g1  = (const float*)d_in[8];
  const float* be1 = (const float*)d_in[9];
  const float* W1  = (const float*)d_in[10];
  const float* b1  = (const float*)d_in[11];
  const float* W2  = (const float*)d_in[12];
  const float* b2  = (const float*)d_in[13];
  const float* g2  = (const float*)d_in[14];
  const float* be2 = (const float*)d_in[15];
  float* out = (float*)d_out;

  int total = in_sizes[0] / 512;
  if (total <= 0) return;
  long long n = (long long)total * 512;

  char* p = (char*)d_ws;
  int*   meta = (int*)p;    p += 16384;
  short* xb   = (short*)p;  p += n*2;
  short* mb   = (short*)p;  p += n*2;
  short* Qb   = (short*)p;  p += n*2;
  short* Kbf  = (short*)p;  p += n*2;
  short* Vtb  = (short*)p;  p += n*2;
  short* attnb= (short*)p;  p += n*2;
  short* woout= (short*)p;  p += n*2;   // reused as mlpart during attention
  short* hb   = (short*)p;  p += n*2;
  short* ffn1 = (short*)p;  p += (long long)total*2048*2;  // reused as Opart
  short* ffn2 = (short*)p;  p += n*2;
  short* WqT  = (short*)p;  p += 512*512*2;
  short* WkT  = (short*)p;  p += 512*512*2;
  short* WvT  = (short*)p;  p += 512*512*2;
  short* WoT  = (short*)p;  p += 512*512*2;
  short* W1T  = (short*)p;  p += 2048*512*2;
  short* W2T  = (short*)p;  p += 512*2048*2;

  prep_kernel<<<1, 256, 0, stream>>>(lxr, lmr, meta);

  long long th = (2*n)/8;
  cvt2bf<<<dim3((unsigned)((th + 255)/256)), dim3(256), 0, stream>>>(x, mem, xb, mb, n);
  cvt_w_t<<<dim3(3072), dim3(256), 0, stream>>>(Wq,Wk,Wv,Wo,W1,W2, WqT,WkT,WvT,WoT,W1T,W2T);

  int mt128 = (total + 127)/128;
  int mt64  = (total + 63)/64;
  gemm_qkv<<<dim3(12, mt64), 256, 0, stream>>>(xb, mb, WqT, WkT, WvT, Qb, Kbf, Vtb, total);

  attn_kernel<<<dim3(2048), 256, 0, stream>>>(Qb, Kbf, Vtb, attnb,
                                              ffn1, (float*)woout, meta, total);
  attn_combine<<<dim3((unsigned)((total + 3)/4)), 256, 0, stream>>>(
      ffn1, (const float*)woout, attnb, meta, total);

  gemm_bt64<<<dim3(4, mt64), 256, 0, stream>>>(attnb, WoT, woout, nullptr, total, 512, 512, 1.f, 0, 0);
  ln_fuse<<<dim3((unsigned)((total + 3)/4)), 256, 0, stream>>>(x, nullptr, woout, g1, be1, hb, nullptr, total);

  gemm_bt<<<dim3(16, mt128), 256, 0, stream>>>(hb,   W1T, ffn1, b1, total, 2048, 512,  1.f, 1, 0);
  gemm_bt64<<<dim3(4, mt64), 256, 0, stream>>>(ffn1, W2T, ffn2, b2, total, 512,  2048, 1.f, 0, 0);
  ln_fuse<<<dim3((unsigned)((total + 3)/4)), 256, 0, stream>>>(nullptr, hb, ffn2, g2, be2, nullptr, out, total);
}